// Round 1
// baseline (2726.794 us; speedup 1.0000x reference)
//
#include <hip/hip_runtime.h>
#include <hip/hip_bf16.h>
#include <math.h>

// ---------------- problem constants ----------------
constexpr int B_ = 2, T_ = 1024, D_ = 768, H_ = 12, L_ = 4, V_ = 32000;
constexpr int M_ = B_ * T_;          // 2048 token rows
constexpr int FF_ = 4 * D_;          // 3072
constexpr int QKVN_ = 3 * D_;        // 2304
#define EMB_SCALE 27.712812921102035f
#define EPS_ 1e-5f

typedef __attribute__((ext_vector_type(8))) short short8_t;
typedef __attribute__((ext_vector_type(4))) float float4_t;

__device__ __forceinline__ float bf2f(__hip_bfloat16 v) { return __bfloat162float(v); }
__device__ __forceinline__ __hip_bfloat16 f2bf(float v) { return __float2bfloat16(v); }

// ---------------- weight convert (plain f32 -> bf16) ----------------
__global__ __launch_bounds__(256) void convert_kernel(
    const float* __restrict__ src, __hip_bfloat16* __restrict__ dst, size_t n)
{
    size_t i = ((size_t)blockIdx.x * 256 + threadIdx.x) * 4;
    if (i + 3 < n) {
        float4 f = *(const float4*)(src + i);
        dst[i + 0] = f2bf(f.x);
        dst[i + 1] = f2bf(f.y);
        dst[i + 2] = f2bf(f.z);
        dst[i + 3] = f2bf(f.w);
    }
}

// ------------- transpose + convert: src f32 [K,N] -> dst bf16 [N,K] -------------
// batched over blockIdx.z (layers). K,N multiples of 32.
__global__ __launch_bounds__(256) void tconv_kernel(
    const float* __restrict__ src, __hip_bfloat16* __restrict__ dst,
    int K, int N, size_t sstride, size_t dstride)
{
    __shared__ float tile[32][33];
    const float* S = src + (size_t)blockIdx.z * sstride;
    __hip_bfloat16* Dd = dst + (size_t)blockIdx.z * dstride;
    int n0 = blockIdx.x * 32, k0 = blockIdx.y * 32;
    int tx = threadIdx.x & 31, ty = threadIdx.x >> 5; // 32 x 8
#pragma unroll
    for (int i = 0; i < 32; i += 8)
        tile[ty + i][tx] = S[(size_t)(k0 + ty + i) * N + n0 + tx];
    __syncthreads();
#pragma unroll
    for (int i = 0; i < 32; i += 8)
        Dd[(size_t)(n0 + ty + i) * K + k0 + tx] = f2bf(tile[tx][ty + i]);
}

// ---------------- embedding ----------------
__global__ __launch_bounds__(256) void embed_kernel(
    const int* __restrict__ idx, const float* __restrict__ wte,
    const float* __restrict__ wpe, float* __restrict__ x)
{
    int row = blockIdx.x, tid = threadIdx.x;
    int t = row & (T_ - 1);
    int tok = idx[row];
#pragma unroll
    for (int i = 0; i < 3; ++i) {
        int c = i * 256 + tid;
        x[(size_t)row * D_ + c] =
            (wte[(size_t)tok * D_ + c] + wpe[(size_t)t * D_ + c]) * EMB_SCALE;
    }
}

// ---------------- DynamicTanh (layernorm stats + w*tanh(alpha*xn)+b) ----------------
__global__ __launch_bounds__(256) void dyt_kernel(
    const float* __restrict__ x, __hip_bfloat16* __restrict__ h,
    const float* __restrict__ w, const float* __restrict__ bb,
    const float* __restrict__ alpha_p)
{
    const int row = blockIdx.x, tid = threadIdx.x;
    const float* xr = x + (size_t)row * D_;
    float v[3];
    float s = 0.f, ss = 0.f;
#pragma unroll
    for (int i = 0; i < 3; ++i) {
        v[i] = xr[i * 256 + tid];
        s += v[i];
        ss += v[i] * v[i];
    }
#pragma unroll
    for (int off = 32; off >= 1; off >>= 1) {
        s  += __shfl_xor(s,  off, 64);
        ss += __shfl_xor(ss, off, 64);
    }
    __shared__ float sh[8];
    int wave = tid >> 6;
    if ((tid & 63) == 0) { sh[wave] = s; sh[wave + 4] = ss; }
    __syncthreads();
    s  = sh[0] + sh[1] + sh[2] + sh[3];
    ss = sh[4] + sh[5] + sh[6] + sh[7];
    float mu = s * (1.f / D_);
    float var = ss * (1.f / D_) - mu * mu;
    float rstd = rsqrtf(var + EPS_);
    float alpha = *alpha_p;
#pragma unroll
    for (int i = 0; i < 3; ++i) {
        int c = i * 256 + tid;
        float xn = (v[i] - mu) * rstd;
        h[(size_t)row * D_ + c] = f2bf(w[c] * tanhf(alpha * xn) + bb[c]);
    }
}

// ---------------- attention: one wave per (b, h, t_q), online softmax ----------------
__global__ __launch_bounds__(64) void attn_kernel(
    const __hip_bfloat16* __restrict__ qkv, __hip_bfloat16* __restrict__ o)
{
    const int tq = blockIdx.x, hh = blockIdx.y, b = blockIdx.z;
    const int lane = threadIdx.x;
    const size_t rs = QKVN_; // row stride in elements
    __shared__ float q_s[64];
    __shared__ float p_s[64];
    const __hip_bfloat16* qrow = qkv + (size_t)(b * T_ + tq) * rs + hh * 64;
    q_s[lane] = bf2f(qrow[lane]) * 0.125f; // 1/sqrt(64)
    __syncthreads();
    float m = -1e30f, l = 0.f, acc = 0.f;
    const __hip_bfloat16* kbase = qkv + (size_t)b * T_ * rs + D_ + hh * 64;
    const __hip_bfloat16* vbase = qkv + (size_t)b * T_ * rs + 2 * D_ + hh * 64;
    for (int t0 = 0; t0 <= tq; t0 += 64) {
        int j = t0 + lane;
        float sc = -1e30f;
        if (j <= tq) {
            const __hip_bfloat16* kr = kbase + (size_t)j * rs;
            float a0 = 0.f;
#pragma unroll
            for (int d = 0; d < 64; ++d) a0 += q_s[d] * bf2f(kr[d]);
            sc = a0;
        }
        float cmax = sc;
#pragma unroll
        for (int off = 32; off >= 1; off >>= 1) cmax = fmaxf(cmax, __shfl_xor(cmax, off, 64));
        float mnew = fmaxf(m, cmax);
        float p = (j <= tq) ? __expf(sc - mnew) : 0.f;
        float alpha = __expf(m - mnew);
        float psum = p;
#pragma unroll
        for (int off = 32; off >= 1; off >>= 1) psum += __shfl_xor(psum, off, 64);
        __syncthreads();          // protect p_s against previous iteration's readers
        p_s[lane] = p;
        __syncthreads();
        l = l * alpha + psum;
        acc *= alpha;
        int jmax = min(64, tq - t0 + 1);
        const __hip_bfloat16* vcol = vbase + (size_t)t0 * rs + lane;
        for (int jj = 0; jj < jmax; ++jj)
            acc += p_s[jj] * bf2f(vcol[(size_t)jj * rs]);
        m = mnew;
    }
    o[(size_t)(b * T_ + tq) * D_ + hh * 64 + lane] = f2bf(acc / l);
}

// ---------------- GEMM: C[M,N] = A[M,K] @ Bt[N,K]^T, bf16 in, f32 acc ----------------
// EPI: 0 = bf16 out (no bias), 1 = f32 out = res + acc + bias,
//      2 = bf16 out = gelu(acc + bias), 3 = f32 out = acc
__device__ __forceinline__ float gelu_exact(float t) {
    return 0.5f * t * (1.0f + erff(t * 0.70710678118654752f));
}

template <int EPI>
__global__ __launch_bounds__(256, 2) void gemm_bt(
    const __hip_bfloat16* __restrict__ A, const __hip_bfloat16* __restrict__ Bt,
    float* __restrict__ outF, __hip_bfloat16* __restrict__ outB,
    const float* __restrict__ bias, const float* __restrict__ res,
    int M, int N, int K)
{
    __shared__ __hip_bfloat16 As[128 * 32];
    __shared__ __hip_bfloat16 Bs[128 * 32];
    const int tid = threadIdx.x;
    const int wave = tid >> 6, lane = tid & 63;
    const int quad = lane >> 4, l16 = lane & 15;
    const int m0 = blockIdx.y * 128, n0 = blockIdx.x * 128;
    const int wm = (wave >> 1) * 64, wn = (wave & 1) * 64;

    float4_t acc[4][4];
#pragma unroll
    for (int i = 0; i < 4; ++i)
#pragma unroll
        for (int j = 0; j < 4; ++j) acc[i][j] = (float4_t){0.f, 0.f, 0.f, 0.f};

    const int r = tid >> 2, c = tid & 3; // staging: row r & r+64, 8-elem chunk c
    for (int k0 = 0; k0 < K; k0 += 32) {
        uint4 a0 = *(const uint4*)(A  + (size_t)(m0 + r)      * K + k0 + c * 8);
        uint4 a1 = *(const uint4*)(A  + (size_t)(m0 + r + 64) * K + k0 + c * 8);
        uint4 b0 = *(const uint4*)(Bt + (size_t)(n0 + r)      * K + k0 + c * 8);
        uint4 b1 = *(const uint4*)(Bt + (size_t)(n0 + r + 64) * K + k0 + c * 8);
        __syncthreads();  // previous iteration's fragment reads complete
        *(uint4*)(As + r * 32 + c * 8)        = a0;
        *(uint4*)(As + (r + 64) * 32 + c * 8) = a1;
        *(uint4*)(Bs + r * 32 + c * 8)        = b0;
        *(uint4*)(Bs + (r + 64) * 32 + c * 8) = b1;
        __syncthreads();
        short8_t af[4], bfv[4];
#pragma unroll
        for (int i = 0; i < 4; ++i) {
            af[i]  = *(const short8_t*)(As + (wm + i * 16 + l16) * 32 + quad * 8);
            bfv[i] = *(const short8_t*)(Bs + (wn + i * 16 + l16) * 32 + quad * 8);
        }
#pragma unroll
        for (int i = 0; i < 4; ++i)
#pragma unroll
            for (int j = 0; j < 4; ++j)
                acc[i][j] = __builtin_amdgcn_mfma_f32_16x16x32_bf16(
                    af[i], bfv[j], acc[i][j], 0, 0, 0);
    }

#pragma unroll
    for (int i = 0; i < 4; ++i) {
#pragma unroll
        for (int j = 0; j < 4; ++j) {
            int colg = n0 + wn + j * 16 + l16;
#pragma unroll
            for (int rg = 0; rg < 4; ++rg) {
                int rowg = m0 + wm + i * 16 + quad * 4 + rg;
                size_t offo = (size_t)rowg * N + colg;
                float v = acc[i][j][rg];
                if (EPI == 0) {
                    outB[offo] = f2bf(v);
                } else if (EPI == 1) {
                    outF[offo] = res[offo] + v + bias[colg];
                } else if (EPI == 2) {
                    outB[offo] = f2bf(gelu_exact(v + bias[colg]));
                } else {
                    outF[offo] = v;
                }
            }
        }
    }
}

// ---------------- launch ----------------
extern "C" void kernel_launch(void* const* d_in, const int* in_sizes, int n_in,
                              void* d_out, int out_size, void* d_ws, size_t ws_size,
                              hipStream_t stream)
{
    const int*   idx   = (const int*)d_in[0];
    const float* wte   = (const float*)d_in[1];
    const float* wpe   = (const float*)d_in[2];
    const float* ln1_a = (const float*)d_in[3];
    const float* ln1_w = (const float*)d_in[4];
    const float* ln1_b = (const float*)d_in[5];
    const float* wq    = (const float*)d_in[6];
    const float* wk    = (const float*)d_in[7];
    const float* wv    = (const float*)d_in[8];
    const float* wo    = (const float*)d_in[9];
    const float* bo    = (const float*)d_in[10];
    const float* ln2_a = (const float*)d_in[11];
    const float* ln2_w = (const float*)d_in[12];
    const float* ln2_b = (const float*)d_in[13];
    const float* w_fc  = (const float*)d_in[14];
    const float* b_fc  = (const float*)d_in[15];
    const float* w_pr  = (const float*)d_in[16];
    const float* b_pr  = (const float*)d_in[17];
    const float* lnf_a = (const float*)d_in[18];
    const float* lnf_w = (const float*)d_in[19];
    const float* lnf_b = (const float*)d_in[20];
    float* out = (float*)d_out;

    char* ws = (char*)d_ws;
    size_t off = 0;
    auto alloc = [&](size_t bytes) -> char* {
        char* p = ws + off;
        off += (bytes + 255) & ~(size_t)255;
        return p;
    };
    __hip_bfloat16* wqkv_t = (__hip_bfloat16*)alloc((size_t)L_ * QKVN_ * D_ * 2);
    __hip_bfloat16* wo_t   = (__hip_bfloat16*)alloc((size_t)L_ * D_ * D_ * 2);
    __hip_bfloat16* wfc_t  = (__hip_bfloat16*)alloc((size_t)L_ * FF_ * D_ * 2);
    __hip_bfloat16* wpr_t  = (__hip_bfloat16*)alloc((size_t)L_ * D_ * FF_ * 2);
    __hip_bfloat16* wte_b  = (__hip_bfloat16*)alloc((size_t)V_ * D_ * 2);
    float*          x      = (float*)alloc((size_t)M_ * D_ * 4);
    __hip_bfloat16* h      = (__hip_bfloat16*)alloc((size_t)M_ * D_ * 2);
    __hip_bfloat16* qkv    = (__hip_bfloat16*)alloc((size_t)M_ * QKVN_ * 2);
    __hip_bfloat16* attno  = (__hip_bfloat16*)alloc((size_t)M_ * D_ * 2);
    __hip_bfloat16* mid    = (__hip_bfloat16*)alloc((size_t)M_ * FF_ * 2);
    (void)ws_size; (void)in_sizes; (void)n_in; (void)out_size;

    // ---- weight prep (bf16, [N,K] layout) ----
    {
        size_t n = (size_t)V_ * D_;
        convert_kernel<<<dim3((unsigned)(n / 1024)), 256, 0, stream>>>(wte, wte_b, n);
    }
    size_t wstride = (size_t)D_ * D_;
    tconv_kernel<<<dim3(24, 24, L_), 256, 0, stream>>>(wq, wqkv_t + 0,            D_, D_, wstride, (size_t)QKVN_ * D_);
    tconv_kernel<<<dim3(24, 24, L_), 256, 0, stream>>>(wk, wqkv_t + (size_t)D_ * D_,   D_, D_, wstride, (size_t)QKVN_ * D_);
    tconv_kernel<<<dim3(24, 24, L_), 256, 0, stream>>>(wv, wqkv_t + (size_t)2 * D_ * D_, D_, D_, wstride, (size_t)QKVN_ * D_);
    tconv_kernel<<<dim3(24, 24, L_), 256, 0, stream>>>(wo, wo_t,                  D_, D_, wstride, wstride);
    tconv_kernel<<<dim3(96, 24, L_), 256, 0, stream>>>(w_fc, wfc_t, D_, FF_, (size_t)D_ * FF_, (size_t)FF_ * D_);
    tconv_kernel<<<dim3(24, 96, L_), 256, 0, stream>>>(w_pr, wpr_t, FF_, D_, (size_t)FF_ * D_, (size_t)D_ * FF_);

    // ---- embedding ----
    embed_kernel<<<dim3(M_), 256, 0, stream>>>(idx, wte, wpe, x);

    // ---- transformer layers ----
    for (int l = 0; l < L_; ++l) {
        dyt_kernel<<<dim3(M_), 256, 0, stream>>>(x, h, ln1_w + l * D_, ln1_b + l * D_, ln1_a + l);
        gemm_bt<0><<<dim3(QKVN_ / 128, M_ / 128), 256, 0, stream>>>(
            h, wqkv_t + (size_t)l * QKVN_ * D_, nullptr, qkv, nullptr, nullptr, M_, QKVN_, D_);
        attn_kernel<<<dim3(T_, H_, B_), 64, 0, stream>>>(qkv, attno);
        gemm_bt<1><<<dim3(D_ / 128, M_ / 128), 256, 0, stream>>>(
            attno, wo_t + (size_t)l * D_ * D_, x, nullptr, bo + l * D_, x, M_, D_, D_);
        dyt_kernel<<<dim3(M_), 256, 0, stream>>>(x, h, ln2_w + l * D_, ln2_b + l * D_, ln2_a + l);
        gemm_bt<2><<<dim3(FF_ / 128, M_ / 128), 256, 0, stream>>>(
            h, wfc_t + (size_t)l * FF_ * D_, nullptr, mid, b_fc + l * FF_, nullptr, M_, FF_, D_);
        gemm_bt<1><<<dim3(D_ / 128, M_ / 128), 256, 0, stream>>>(
            mid, wpr_t + (size_t)l * D_ * FF_, x, nullptr, b_pr + l * D_, x, M_, D_, FF_);
    }

    // ---- final DyT + lm_head ----
    dyt_kernel<<<dim3(M_), 256, 0, stream>>>(x, h, lnf_w, lnf_b, lnf_a);
    gemm_bt<3><<<dim3(V_ / 128, M_ / 128), 256, 0, stream>>>(
        h, wte_b, out, nullptr, nullptr, nullptr, M_, V_, D_);
}

// Round 2
// 1302.886 us; speedup vs baseline: 2.0929x; 2.0929x over previous
//
#include <hip/hip_runtime.h>
#include <hip/hip_bf16.h>
#include <math.h>

// ---------------- problem constants ----------------
constexpr int B_ = 2, T_ = 1024, D_ = 768, H_ = 12, L_ = 4, V_ = 32000;
constexpr int M_ = B_ * T_;          // 2048 token rows
constexpr int FF_ = 4 * D_;          // 3072
constexpr int QKVN_ = 3 * D_;        // 2304
#define EMB_SCALE 27.712812921102035f
#define EPS_ 1e-5f

typedef __attribute__((ext_vector_type(8))) short short8_t;
typedef __attribute__((ext_vector_type(4))) float float4_t;

__device__ __forceinline__ float bf2f(__hip_bfloat16 v) { return __bfloat162float(v); }
__device__ __forceinline__ __hip_bfloat16 f2bf(float v) { return __float2bfloat16(v); }

// async global->LDS, 16B per lane; lds dest is wave-uniform base + lane*16
__device__ __forceinline__ void gl_lds16(const __hip_bfloat16* g, __hip_bfloat16* l) {
    __builtin_amdgcn_global_load_lds(
        (const __attribute__((address_space(1))) void*)g,
        (__attribute__((address_space(3))) void*)l, 16, 0, 0);
}

// ---------------- weight convert (plain f32 -> bf16) ----------------
__global__ __launch_bounds__(256) void convert_kernel(
    const float* __restrict__ src, __hip_bfloat16* __restrict__ dst, size_t n)
{
    size_t i = ((size_t)blockIdx.x * 256 + threadIdx.x) * 4;
    if (i + 3 < n) {
        float4 f = *(const float4*)(src + i);
        dst[i + 0] = f2bf(f.x);
        dst[i + 1] = f2bf(f.y);
        dst[i + 2] = f2bf(f.z);
        dst[i + 3] = f2bf(f.w);
    }
}

// ------------- transpose + convert: src f32 [K,N] -> dst bf16 [N,K] -------------
__global__ __launch_bounds__(256) void tconv_kernel(
    const float* __restrict__ src, __hip_bfloat16* __restrict__ dst,
    int K, int N, size_t sstride, size_t dstride)
{
    __shared__ float tile[32][33];
    const float* S = src + (size_t)blockIdx.z * sstride;
    __hip_bfloat16* Dd = dst + (size_t)blockIdx.z * dstride;
    int n0 = blockIdx.x * 32, k0 = blockIdx.y * 32;
    int tx = threadIdx.x & 31, ty = threadIdx.x >> 5; // 32 x 8
#pragma unroll
    for (int i = 0; i < 32; i += 8)
        tile[ty + i][tx] = S[(size_t)(k0 + ty + i) * N + n0 + tx];
    __syncthreads();
#pragma unroll
    for (int i = 0; i < 32; i += 8)
        Dd[(size_t)(n0 + ty + i) * K + k0 + tx] = f2bf(tile[tx][ty + i]);
}

// ---------------- embedding ----------------
__global__ __launch_bounds__(256) void embed_kernel(
    const int* __restrict__ idx, const float* __restrict__ wte,
    const float* __restrict__ wpe, float* __restrict__ x)
{
    int row = blockIdx.x, tid = threadIdx.x;
    int t = row & (T_ - 1);
    int tok = idx[row];
#pragma unroll
    for (int i = 0; i < 3; ++i) {
        int c = i * 256 + tid;
        x[(size_t)row * D_ + c] =
            (wte[(size_t)tok * D_ + c] + wpe[(size_t)t * D_ + c]) * EMB_SCALE;
    }
}

// ---------------- DynamicTanh ----------------
__global__ __launch_bounds__(256) void dyt_kernel(
    const float* __restrict__ x, __hip_bfloat16* __restrict__ h,
    const float* __restrict__ w, const float* __restrict__ bb,
    const float* __restrict__ alpha_p)
{
    const int row = blockIdx.x, tid = threadIdx.x;
    const float* xr = x + (size_t)row * D_;
    float v[3];
    float s = 0.f, ss = 0.f;
#pragma unroll
    for (int i = 0; i < 3; ++i) {
        v[i] = xr[i * 256 + tid];
        s += v[i];
        ss += v[i] * v[i];
    }
#pragma unroll
    for (int off = 32; off >= 1; off >>= 1) {
        s  += __shfl_xor(s,  off, 64);
        ss += __shfl_xor(ss, off, 64);
    }
    __shared__ float sh[8];
    int wave = tid >> 6;
    if ((tid & 63) == 0) { sh[wave] = s; sh[wave + 4] = ss; }
    __syncthreads();
    s  = sh[0] + sh[1] + sh[2] + sh[3];
    ss = sh[4] + sh[5] + sh[6] + sh[7];
    float mu = s * (1.f / D_);
    float var = ss * (1.f / D_) - mu * mu;
    float rstd = rsqrtf(var + EPS_);
    float alpha = *alpha_p;
#pragma unroll
    for (int i = 0; i < 3; ++i) {
        int c = i * 256 + tid;
        float xn = (v[i] - mu) * rstd;
        h[(size_t)row * D_ + c] = f2bf(w[c] * tanhf(alpha * xn) + bb[c]);
    }
}

// ---------------- flash attention: 256 thr, 4 waves, Q-tile 64 rows ----------------
// qkv rows [M, 2304]: q at +0, k at +768, v at +1536. o rows [M, 768].
constexpr int LSTR = 72;   // LDS row stride (elements); 144 B, 16B-aligned rows

__global__ __launch_bounds__(256) void fattn_kernel(
    const __hip_bfloat16* __restrict__ qkv, __hip_bfloat16* __restrict__ o)
{
    const int qt = gridDim.x - 1 - blockIdx.x;   // longest blocks first
    const int hh = blockIdx.y, b = blockIdx.z;
    const int q0 = qt * 64;
    const int tid = threadIdx.x;
    const int wave = tid >> 6, lane = tid & 63;
    const int quad = lane >> 4, l16 = lane & 15;
    const size_t rs = QKVN_;

    __shared__ __hip_bfloat16 Ks[64 * LSTR];      // [k][d]
    __shared__ __hip_bfloat16 Vts[64 * LSTR];     // [d][k] (transposed)
    __shared__ __hip_bfloat16 Ps[4][16 * LSTR];   // per-wave P strip [m][k]

    // Q A-frags: rows q0 + wave*16 + l16, d chunks quad*8 (+32)
    const __hip_bfloat16* qrow = qkv + (size_t)(b * T_ + q0 + wave * 16 + l16) * rs + hh * 64;
    short8_t qf0 = *(const short8_t*)(qrow + quad * 8);
    short8_t qf1 = *(const short8_t*)(qrow + 32 + quad * 8);

    float4_t Oacc[4];
#pragma unroll
    for (int j = 0; j < 4; ++j) Oacc[j] = (float4_t){0.f, 0.f, 0.f, 0.f};
    float mrow[4], lrow[4];
#pragma unroll
    for (int r = 0; r < 4; ++r) { mrow[r] = -1e30f; lrow[r] = 0.f; }

    const __hip_bfloat16* kbase = qkv + (size_t)b * T_ * rs + D_ + hh * 64;
    const __hip_bfloat16* vbase = qkv + (size_t)b * T_ * rs + 2 * D_ + hh * 64;

    const int sr = tid >> 2;            // K staging: row 0..63
    const int sc = (tid & 3) * 8;       // K staging: d chunk
    const int vr = lane;                // V staging: row (k)
    const int vc0 = wave * 16;          // V staging: d chunk start

    for (int kt = 0; kt <= qt; ++kt) {
        const int kt0 = kt * 64;
        uint4 kv0 = *(const uint4*)(kbase + (size_t)(kt0 + sr) * rs + sc);
        uint4 kv1 = *(const uint4*)(kbase + (size_t)(kt0 + sr) * rs + sc + 32);
        uint4 vv0 = *(const uint4*)(vbase + (size_t)(kt0 + vr) * rs + vc0);
        uint4 vv1 = *(const uint4*)(vbase + (size_t)(kt0 + vr) * rs + vc0 + 8);
        __syncthreads();   // WAR: prev tile's frag reads done
        *(uint4*)(Ks + sr * LSTR + sc)      = kv0;
        *(uint4*)(Ks + sr * LSTR + sc + 32) = kv1;
        {
            const __hip_bfloat16* vp = (const __hip_bfloat16*)&vv0;
#pragma unroll
            for (int i = 0; i < 8; ++i) Vts[(vc0 + i) * LSTR + vr] = vp[i];
            vp = (const __hip_bfloat16*)&vv1;
#pragma unroll
            for (int i = 0; i < 8; ++i) Vts[(vc0 + 8 + i) * LSTR + vr] = vp[i];
        }
        __syncthreads();

        // ---- S strip = Q(16) x K^T(64) ----
        float4_t S[4];
#pragma unroll
        for (int jt = 0; jt < 4; ++jt) {
            short8_t kf0 = *(const short8_t*)(Ks + (jt * 16 + l16) * LSTR + quad * 8);
            short8_t kf1 = *(const short8_t*)(Ks + (jt * 16 + l16) * LSTR + 32 + quad * 8);
            float4_t s = (float4_t){0.f, 0.f, 0.f, 0.f};
            s = __builtin_amdgcn_mfma_f32_16x16x32_bf16(qf0, kf0, s, 0, 0, 0);
            s = __builtin_amdgcn_mfma_f32_16x16x32_bf16(qf1, kf1, s, 0, 0, 0);
            S[jt] = s;
        }

        // ---- scale + causal mask (diag tile only) ----
        if (kt == qt) {
#pragma unroll
            for (int jt = 0; jt < 4; ++jt)
#pragma unroll
                for (int r = 0; r < 4; ++r) {
                    int qg = wave * 16 + quad * 4 + r;
                    int kg = jt * 16 + l16;
                    S[jt][r] = (kg > qg) ? -1e30f : S[jt][r] * 0.125f;
                }
        } else {
#pragma unroll
            for (int jt = 0; jt < 4; ++jt)
#pragma unroll
                for (int r = 0; r < 4; ++r) S[jt][r] *= 0.125f;
        }

        // ---- online softmax (rows = quad*4+r, reduce across 16-lane group) ----
        float mnew[4], alphav[4];
#pragma unroll
        for (int r = 0; r < 4; ++r) {
            float mx = fmaxf(fmaxf(S[0][r], S[1][r]), fmaxf(S[2][r], S[3][r]));
            mx = fmaxf(mx, __shfl_xor(mx, 1, 64));
            mx = fmaxf(mx, __shfl_xor(mx, 2, 64));
            mx = fmaxf(mx, __shfl_xor(mx, 4, 64));
            mx = fmaxf(mx, __shfl_xor(mx, 8, 64));
            mnew[r] = fmaxf(mrow[r], mx);
            alphav[r] = __expf(mrow[r] - mnew[r]);
            mrow[r] = mnew[r];
        }
        float psum[4] = {0.f, 0.f, 0.f, 0.f};
#pragma unroll
        for (int jt = 0; jt < 4; ++jt)
#pragma unroll
            for (int r = 0; r < 4; ++r) {
                float p = __expf(S[jt][r] - mnew[r]);
                S[jt][r] = p;
                psum[r] += p;
            }
#pragma unroll
        for (int r = 0; r < 4; ++r) {
            float ps = psum[r];
            ps += __shfl_xor(ps, 1, 64);
            ps += __shfl_xor(ps, 2, 64);
            ps += __shfl_xor(ps, 4, 64);
            ps += __shfl_xor(ps, 8, 64);
            lrow[r] = lrow[r] * alphav[r] + ps;
        }

        // ---- P strip: C-layout regs -> LDS [m][k] (own wave only, no barrier) ----
        __hip_bfloat16* ps_base = Ps[wave];
#pragma unroll
        for (int jt = 0; jt < 4; ++jt)
#pragma unroll
            for (int r = 0; r < 4; ++r)
                ps_base[(quad * 4 + r) * LSTR + jt * 16 + l16] = f2bf(S[jt][r]);

        // ---- rescale O, then O += P @ V ----
#pragma unroll
        for (int j = 0; j < 4; ++j)
#pragma unroll
            for (int r = 0; r < 4; ++r) Oacc[j][r] *= alphav[r];

        short8_t pf0 = *(const short8_t*)(ps_base + l16 * LSTR + quad * 8);
        short8_t pf1 = *(const short8_t*)(ps_base + l16 * LSTR + 32 + quad * 8);
#pragma unroll
        for (int j = 0; j < 4; ++j) {
            short8_t vf0 = *(const short8_t*)(Vts + (j * 16 + l16) * LSTR + quad * 8);
            short8_t vf1 = *(const short8_t*)(Vts + (j * 16 + l16) * LSTR + 32 + quad * 8);
            Oacc[j] = __builtin_amdgcn_mfma_f32_16x16x32_bf16(pf0, vf0, Oacc[j], 0, 0, 0);
            Oacc[j] = __builtin_amdgcn_mfma_f32_16x16x32_bf16(pf1, vf1, Oacc[j], 0, 0, 0);
        }
    }

    // ---- epilogue: O /= l, write ----
    float inv_l[4];
#pragma unroll
    for (int r = 0; r < 4; ++r) inv_l[r] = 1.f / lrow[r];
    __hip_bfloat16* orow = o + (size_t)(b * T_ + q0 + wave * 16) * D_ + hh * 64;
#pragma unroll
    for (int j = 0; j < 4; ++j)
#pragma unroll
        for (int r = 0; r < 4; ++r)
            orow[(size_t)(quad * 4 + r) * D_ + j * 16 + l16] = f2bf(Oacc[j][r] * inv_l[r]);
}

// ---------------- GEMM: C[M,N] = A[M,K] @ Bt[N,K]^T, bf16 in, f32 acc ----------------
// EPI: 0 = bf16 out (no bias), 1 = f32 out = res + acc + bias,
//      2 = bf16 out = gelu(acc + bias), 3 = f32 out = acc
__device__ __forceinline__ float gelu_exact(float t) {
    return 0.5f * t * (1.0f + erff(t * 0.70710678118654752f));
}

template <int EPI>
__global__ __launch_bounds__(256, 2) void gemm_bt(
    const __hip_bfloat16* __restrict__ A, const __hip_bfloat16* __restrict__ Bt,
    float* __restrict__ outF, __hip_bfloat16* __restrict__ outB,
    const float* __restrict__ bias, const float* __restrict__ res,
    int M, int N, int K)
{
    __shared__ __hip_bfloat16 As[128 * 32];
    __shared__ __hip_bfloat16 Bs[128 * 32];
    const int tid = threadIdx.x;
    const int wave = tid >> 6, lane = tid & 63;
    const int quad = lane >> 4, l16 = lane & 15;
    const int m0 = blockIdx.y * 128, n0 = blockIdx.x * 128;
    const int wm = (wave >> 1) * 64, wn = (wave & 1) * 64;

    float4_t acc[4][4];
#pragma unroll
    for (int i = 0; i < 4; ++i)
#pragma unroll
        for (int j = 0; j < 4; ++j) acc[i][j] = (float4_t){0.f, 0.f, 0.f, 0.f};

    // global_load_lds staging: wave w stages As/Bs rows [w*16, w*16+16) and +64.
    // lane -> (row lr, 16B chunk lc); lds dest = wave-uniform base + lane*16B.
    const int lr = lane >> 2, lc = (lane & 3) * 8;
    const __hip_bfloat16* ga0 = A  + (size_t)(m0 + wave * 16 + lr) * K + lc;
    const __hip_bfloat16* ga1 = A  + (size_t)(m0 + 64 + wave * 16 + lr) * K + lc;
    const __hip_bfloat16* gb0 = Bt + (size_t)(n0 + wave * 16 + lr) * K + lc;
    const __hip_bfloat16* gb1 = Bt + (size_t)(n0 + 64 + wave * 16 + lr) * K + lc;
    __hip_bfloat16* la0 = As + (wave * 16) * 32;
    __hip_bfloat16* la1 = As + (64 + wave * 16) * 32;
    __hip_bfloat16* lb0 = Bs + (wave * 16) * 32;
    __hip_bfloat16* lb1 = Bs + (64 + wave * 16) * 32;

    for (int k0 = 0; k0 < K; k0 += 32) {
        __syncthreads();  // prev iteration's fragment reads complete
        gl_lds16(ga0 + k0, la0);
        gl_lds16(ga1 + k0, la1);
        gl_lds16(gb0 + k0, lb0);
        gl_lds16(gb1 + k0, lb1);
        __syncthreads();  // drains vmcnt(0): staged data visible
        short8_t af[4], bfv[4];
#pragma unroll
        for (int i = 0; i < 4; ++i) {
            af[i]  = *(const short8_t*)(As + (wm + i * 16 + l16) * 32 + quad * 8);
            bfv[i] = *(const short8_t*)(Bs + (wn + i * 16 + l16) * 32 + quad * 8);
        }
#pragma unroll
        for (int i = 0; i < 4; ++i)
#pragma unroll
            for (int j = 0; j < 4; ++j)
                acc[i][j] = __builtin_amdgcn_mfma_f32_16x16x32_bf16(
                    af[i], bfv[j], acc[i][j], 0, 0, 0);
    }

#pragma unroll
    for (int i = 0; i < 4; ++i) {
#pragma unroll
        for (int j = 0; j < 4; ++j) {
            int colg = n0 + wn + j * 16 + l16;
#pragma unroll
            for (int rg = 0; rg < 4; ++rg) {
                int rowg = m0 + wm + i * 16 + quad * 4 + rg;
                size_t offo = (size_t)rowg * N + colg;
                float v = acc[i][j][rg];
                if (EPI == 0) {
                    outB[offo] = f2bf(v);
                } else if (EPI == 1) {
                    outF[offo] = res[offo] + v + bias[colg];
                } else if (EPI == 2) {
                    outB[offo] = f2bf(gelu_exact(v + bias[colg]));
                } else {
                    outF[offo] = v;
                }
            }
        }
    }
}

// ---------------- launch ----------------
extern "C" void kernel_launch(void* const* d_in, const int* in_sizes, int n_in,
                              void* d_out, int out_size, void* d_ws, size_t ws_size,
                              hipStream_t stream)
{
    const int*   idx   = (const int*)d_in[0];
    const float* wte   = (const float*)d_in[1];
    const float* wpe   = (const float*)d_in[2];
    const float* ln1_a = (const float*)d_in[3];
    const float* ln1_w = (const float*)d_in[4];
    const float* ln1_b = (const float*)d_in[5];
    const float* wq    = (const float*)d_in[6];
    const float* wk    = (const float*)d_in[7];
    const float* wv    = (const float*)d_in[8];
    const float* wo    = (const float*)d_in[9];
    const float* bo    = (const float*)d_in[10];
    const float* ln2_a = (const float*)d_in[11];
    const float* ln2_w = (const float*)d_in[12];
    const float* ln2_b = (const float*)d_in[13];
    const float* w_fc  = (const float*)d_in[14];
    const float* b_fc  = (const float*)d_in[15];
    const float* w_pr  = (const float*)d_in[16];
    const float* b_pr  = (const float*)d_in[17];
    const float* lnf_a = (const float*)d_in[18];
    const float* lnf_w = (const float*)d_in[19];
    const float* lnf_b = (const float*)d_in[20];
    float* out = (float*)d_out;

    char* ws = (char*)d_ws;
    size_t off = 0;
    auto alloc = [&](size_t bytes) -> char* {
        char* p = ws + off;
        off += (bytes + 255) & ~(size_t)255;
        return p;
    };
    __hip_bfloat16* wqkv_t = (__hip_bfloat16*)alloc((size_t)L_ * QKVN_ * D_ * 2);
    __hip_bfloat16* wo_t   = (__hip_bfloat16*)alloc((size_t)L_ * D_ * D_ * 2);
    __hip_bfloat16* wfc_t  = (__hip_bfloat16*)alloc((size_t)L_ * FF_ * D_ * 2);
    __hip_bfloat16* wpr_t  = (__hip_bfloat16*)alloc((size_t)L_ * D_ * FF_ * 2);
    __hip_bfloat16* wte_b  = (__hip_bfloat16*)alloc((size_t)V_ * D_ * 2);
    float*          x      = (float*)alloc((size_t)M_ * D_ * 4);
    __hip_bfloat16* h      = (__hip_bfloat16*)alloc((size_t)M_ * D_ * 2);
    __hip_bfloat16* qkv    = (__hip_bfloat16*)alloc((size_t)M_ * QKVN_ * 2);
    __hip_bfloat16* attno  = (__hip_bfloat16*)alloc((size_t)M_ * D_ * 2);
    __hip_bfloat16* mid    = (__hip_bfloat16*)alloc((size_t)M_ * FF_ * 2);
    (void)ws_size; (void)in_sizes; (void)n_in; (void)out_size;

    // ---- weight prep (bf16, [N,K] layout) ----
    {
        size_t n = (size_t)V_ * D_;
        convert_kernel<<<dim3((unsigned)(n / 1024)), 256, 0, stream>>>(wte, wte_b, n);
    }
    size_t wstride = (size_t)D_ * D_;
    tconv_kernel<<<dim3(24, 24, L_), 256, 0, stream>>>(wq, wqkv_t + 0,            D_, D_, wstride, (size_t)QKVN_ * D_);
    tconv_kernel<<<dim3(24, 24, L_), 256, 0, stream>>>(wk, wqkv_t + (size_t)D_ * D_,   D_, D_, wstride, (size_t)QKVN_ * D_);
    tconv_kernel<<<dim3(24, 24, L_), 256, 0, stream>>>(wv, wqkv_t + (size_t)2 * D_ * D_, D_, D_, wstride, (size_t)QKVN_ * D_);
    tconv_kernel<<<dim3(24, 24, L_), 256, 0, stream>>>(wo, wo_t,                  D_, D_, wstride, wstride);
    tconv_kernel<<<dim3(96, 24, L_), 256, 0, stream>>>(w_fc, wfc_t, D_, FF_, (size_t)D_ * FF_, (size_t)FF_ * D_);
    tconv_kernel<<<dim3(24, 96, L_), 256, 0, stream>>>(w_pr, wpr_t, FF_, D_, (size_t)FF_ * D_, (size_t)D_ * FF_);

    // ---- embedding ----
    embed_kernel<<<dim3(M_), 256, 0, stream>>>(idx, wte, wpe, x);

    // ---- transformer layers ----
    for (int l = 0; l < L_; ++l) {
        dyt_kernel<<<dim3(M_), 256, 0, stream>>>(x, h, ln1_w + l * D_, ln1_b + l * D_, ln1_a + l);
        gemm_bt<0><<<dim3(QKVN_ / 128, M_ / 128), 256, 0, stream>>>(
            h, wqkv_t + (size_t)l * QKVN_ * D_, nullptr, qkv, nullptr, nullptr, M_, QKVN_, D_);
        fattn_kernel<<<dim3(T_ / 64, H_, B_), 256, 0, stream>>>(qkv, attno);
        gemm_bt<1><<<dim3(D_ / 128, M_ / 128), 256, 0, stream>>>(
            attno, wo_t + (size_t)l * D_ * D_, x, nullptr, bo + l * D_, x, M_, D_, D_);
        dyt_kernel<<<dim3(M_), 256, 0, stream>>>(x, h, ln2_w + l * D_, ln2_b + l * D_, ln2_a + l);
        gemm_bt<2><<<dim3(FF_ / 128, M_ / 128), 256, 0, stream>>>(
            h, wfc_t + (size_t)l * FF_ * D_, nullptr, mid, b_fc + l * FF_, nullptr, M_, FF_, D_);
        gemm_bt<1><<<dim3(D_ / 128, M_ / 128), 256, 0, stream>>>(
            mid, wpr_t + (size_t)l * D_ * FF_, x, nullptr, b_pr + l * D_, x, M_, D_, FF_);
    }

    // ---- final DyT + lm_head ----
    dyt_kernel<<<dim3(M_), 256, 0, stream>>>(x, h, lnf_w, lnf_b, lnf_a);
    gemm_bt<3><<<dim3(V_ / 128, M_ / 128), 256, 0, stream>>>(
        h, wte_b, out, nullptr, nullptr, nullptr, M_, V_, D_);
}